// Round 8
// baseline (173.322 us; speedup 1.0000x reference)
//
#include <hip/hip_runtime.h>

#define EPSV 1e-5f

// Workspace layout (floats):
//   kbuf @ 0     : [b][g][c][l]  8*4*8*49 = 12544
//   W    @ 12544 : [b][g][o<74][c<8]      = 18944   (W = proj_w @ k^T)
//   wq2  @ 31488 : [i][o] 32*32 (BN+scale folded)   = 1024
//   q0   @ 32512 : [o] 32  (folded BN bias * 0.25)  = 32
//   dyT  @ 32544 : [i][o] 64*64                      = 4096
#define OFF_W    12544
#define OFF_WQ2  31488
#define OFF_Q0   32512
#define OFF_DYT  32544

typedef float f4u __attribute__((ext_vector_type(4), aligned(4)));

// ---------------------------------------------------------------------------
// Merged: blocks 0..55 = pool kctx->7x7 + wk conv + BN (kbuf [b][g][c][l]);
// blocks 56..63 = weight prep (wq2/q0 folded BN, dyT transpose).
// ---------------------------------------------------------------------------
__global__ __launch_bounds__(256) void pool_prep_kernel(
    const float* __restrict__ x,
    const float* __restrict__ wk_w, const float* __restrict__ wk_g,
    const float* __restrict__ wk_b, const float* __restrict__ wk_m,
    const float* __restrict__ wk_v,
    const float* __restrict__ wq_w, const float* __restrict__ wq_g,
    const float* __restrict__ wq_b, const float* __restrict__ wq_m,
    const float* __restrict__ wq_v,
    const float* __restrict__ dy_w,
    float* __restrict__ ws)
{
  __shared__ float s_tmp[32 * 64];
  __shared__ float s_kp[32 * 7];
  const int tid = threadIdx.x;

  if (blockIdx.x >= 56) {
    const int t = (blockIdx.x - 56) * 256 + tid;  // 0..2047
    for (int idx = t; idx < 1056; idx += 2048) {
      if (idx < 1024) {
        const int i = idx >> 5, o = idx & 31;
        const float s = wq_g[o] * rsqrtf(wq_v[o] + EPSV);
        ws[OFF_WQ2 + idx] = 0.25f * s * wq_w[o * 32 + i];
      } else {
        const int o = idx - 1024;
        const float s = wq_g[o] * rsqrtf(wq_v[o] + EPSV);
        ws[OFF_Q0 + o] = 0.25f * (wq_b[o] - wq_m[o] * s);
      }
    }
    for (int idx = t; idx < 4096; idx += 2048) {
      const int i = idx >> 6, o = idx & 63;
      ws[OFF_DYT + idx] = dy_w[o * 64 + i];
    }
    return;
  }

  const int b = blockIdx.x / 7;
  const int p = blockIdx.x % 7;
  const int sh = (p * 64) / 7, eh = ((p + 1) * 64 + 6) / 7;
  const float invH = 1.0f / (float)(eh - sh);
  for (int idx = tid; idx < 2048; idx += 256) {
    const int c = idx >> 6, ww = idx & 63;
    const float* xp = x + ((size_t)(b * 64 + 32 + c)) * 4096 + ww;
    float s = 0.f;
    for (int hh = sh; hh < eh; ++hh) s += xp[hh * 64];
    s_tmp[idx] = s * invH;
  }
  __syncthreads();
  if (tid < 224) {
    const int c = tid / 7, q = tid % 7;
    const int sw = (q * 64) / 7, ew = ((q + 1) * 64 + 6) / 7;
    float s = 0.f;
    for (int ww = sw; ww < ew; ++ww) s += s_tmp[c * 64 + ww];
    s_kp[c * 7 + q] = s / (float)(ew - sw);
  }
  __syncthreads();
  if (tid < 224) {
    const int o = tid / 7, q = tid % 7;
    float s = 0.f;
#pragma unroll
    for (int i = 0; i < 32; i++) s += wk_w[o * 32 + i] * s_kp[i * 7 + q];
    const float sc = wk_g[o] * rsqrtf(wk_v[o] + EPSV);
    const int g = o >> 3, c = o & 7, l = p * 7 + q;
    ws[(((size_t)b * 4 + g) * 8 + c) * 49 + l] = (s - wk_m[o]) * sc + wk_b[o];
  }
}

// ---------------------------------------------------------------------------
// W[bg][o][c] = sum_l proj_w[o][l] * k[bg][c][l].
// ---------------------------------------------------------------------------
__global__ __launch_bounds__(256) void fold_w_kernel(
    const float* __restrict__ proj_w, const float* __restrict__ ws_in,
    float* __restrict__ Wout)
{
  const int bg = blockIdx.x;
  const int tid = threadIdx.x;
  __shared__ float s_k[392];
  for (int i = tid; i < 392; i += 256) s_k[i] = ws_in[(size_t)bg * 392 + i];
  __syncthreads();
  for (int idx = tid; idx < 592; idx += 256) {
    const int o = idx >> 3, c = idx & 7;
    float s = 0.f;
#pragma unroll
    for (int l = 0; l < 49; l++) s += proj_w[o * 49 + l] * s_k[c * 49 + l];
    Wout[(size_t)bg * 592 + idx] = s;
  }
}

// ---------------------------------------------------------------------------
// Partial attention: logits for kernel rows [R0,R1), exp, partial denom and
// partial UNSCALED AV accumulator. Softmax denom and AV sum are additive
// across row-subsets, so two threads per (branch,head,pixel) combine exactly.
// ---------------------------------------------------------------------------
template <int K, int R0, int R1, int PBASE>
__device__ __forceinline__ void attn_part(
    const float* __restrict__ Wr, const float* __restrict__ proj_b,
    const float* __restrict__ rp, const float* __restrict__ vb,
    int si, int sj, const float* q8, float* acc, float& den)
{
  constexpr int RS = 2 * K - 1;
  constexpr int NP = (R1 - R0) * K;
  float l[NP];
#pragma unroll
  for (int i = R0; i < R1; i++)
#pragma unroll
    for (int j = 0; j < K; j++) {
      const int p = i * K + j;
      const float* wo = Wr + (PBASE + p) * 8;
      float s = proj_b[PBASE + p];
#pragma unroll
      for (int c = 0; c < 8; c++) s += wo[c] * q8[c];
      l[(i - R0) * K + j] = s + rp[i * RS + j];
    }
  float p0 = 0.f, p1 = 0.f, p2 = 0.f, p3 = 0.f;
#pragma unroll
  for (int o = 0; o < NP; o++) {
    const float e = __expf(l[o]);
    l[o] = e;
    if ((o & 3) == 0) p0 += e;
    else if ((o & 3) == 1) p1 += e;
    else if ((o & 3) == 2) p2 += e;
    else p3 += e;
  }
  den = (p0 + p1) + (p2 + p3);
#pragma unroll
  for (int c = 0; c < 8; c++) acc[c] = 0.f;
#pragma unroll
  for (int i = R0; i < R1; i++) {
    const float* vr0 = vb + (si + i) * 64 + sj;
#pragma unroll
    for (int c = 0; c < 8; c++) {
      const float* vr = vr0 + c * 4096;
      if constexpr (K == 5) {
        const f4u f = *(const f4u*)vr;
        const float v4 = vr[4];
        acc[c] += l[(i - R0) * 5 + 0] * f.x + l[(i - R0) * 5 + 1] * f.y +
                  l[(i - R0) * 5 + 2] * f.z + l[(i - R0) * 5 + 3] * f.w +
                  l[(i - R0) * 5 + 4] * v4;
      } else {
        const f4u fa = *(const f4u*)vr;
        const f4u fb = *(const f4u*)(vr + 3);
        acc[c] += l[(i - R0) * 7 + 0] * fa.x + l[(i - R0) * 7 + 1] * fa.y +
                  l[(i - R0) * 7 + 2] * fa.z + l[(i - R0) * 7 + 3] * fa.w +
                  l[(i - R0) * 7 + 4] * fb.y + l[(i - R0) * 7 + 5] * fb.z +
                  l[(i - R0) * 7 + 6] * fb.w;
      }
    }
  }
}

// ---------------------------------------------------------------------------
// Fused main. Block = 1024 threads = 2 halves x 2 branches x 4 heads x 64 w,
// one image row per block. 8192 waves total (full machine). Halves combine
// partial denom + partial AV through LDS, then fused final conv + BN.
// ---------------------------------------------------------------------------
__global__ __launch_bounds__(1024, 4) void contmix_main(
    const float* __restrict__ x,
    const float* __restrict__ proj_b,
    const float* __restrict__ rpb1, const float* __restrict__ rpb2,
    const float* __restrict__ dy_g, const float* __restrict__ dy_b,
    const float* __restrict__ dy_m, const float* __restrict__ dy_v,
    const float* __restrict__ ws,
    float* __restrict__ out)
{
  __shared__ float s_val[64 * 64];  // [ch][w]: half-0 partial, then final
  __shared__ float s_den[512];      // [br][g][w] half-0 partial denom
  __shared__ float s_rpb1[324];
  __shared__ float s_rpb2[676];

  const int b = blockIdx.x >> 6;
  const int h = blockIdx.x & 63;
  const int tid = threadIdx.x;
  const int w = tid & 63;
  const int gu  = __builtin_amdgcn_readfirstlane((tid >> 6) & 3);
  const int bru = __builtin_amdgcn_readfirstlane((tid >> 8) & 1);
  const int hfu = __builtin_amdgcn_readfirstlane(tid >> 9);

  for (int i = tid; i < 324; i += 1024) s_rpb1[i] = rpb1[i];
  for (int i = tid; i < 676; i += 1024) s_rpb2[i] = rpb2[i];
  __syncthreads();

  const float* xb = x + (size_t)b * 64 * 4096;

  // ---- q8 (BN+scale pre-folded into wq2/q0) ----
  float q8[8];
  {
    const float* q0 = ws + OFF_Q0 + gu * 8;
#pragma unroll
    for (int o = 0; o < 8; o++) q8[o] = q0[o];
    const float* wq2 = ws + OFF_WQ2 + gu * 8;
#pragma unroll
    for (int i = 0; i < 32; i++) {
      const float xv = xb[i * 4096 + h * 64 + w];
#pragma unroll
      for (int o = 0; o < 8; o++) q8[o] += wq2[i * 32 + o] * xv;
    }
  }

  const float* Wr = ws + OFF_W + (size_t)(b * 4 + gu) * 592;  // uniform
  const int ph = 63 - h, pw = 63 - w;

  float acc[8];
  float den;
  if (bru == 0) {
    const int bih = ph - min(max(ph - 2, 0), 59);
    const int biw = pw - min(max(pw - 2, 0), 59);
    const int si = min(max(h - 2, 0), 59), sj = min(max(w - 2, 0), 59);
    const float* rp = s_rpb1 + gu * 81 + bih * 9 + biw;
    const float* vb = xb + gu * 8 * 4096;
    if (hfu == 0)
      attn_part<5, 0, 3, 0>(Wr, proj_b, rp, vb, si, sj, q8, acc, den);
    else
      attn_part<5, 3, 5, 0>(Wr, proj_b, rp, vb, si, sj, q8, acc, den);
  } else {
    const int bih = ph - min(max(ph - 3, 0), 57);
    const int biw = pw - min(max(pw - 3, 0), 57);
    const int si = min(max(h - 3, 0), 57), sj = min(max(w - 3, 0), 57);
    const float* rp = s_rpb2 + gu * 169 + bih * 13 + biw;
    const float* vb = xb + (32 + gu * 8) * 4096;
    if (hfu == 0)
      attn_part<7, 0, 4, 25>(Wr, proj_b, rp, vb, si, sj, q8, acc, den);
    else
      attn_part<7, 4, 7, 25>(Wr, proj_b, rp, vb, si, sj, q8, acc, den);
  }

  const int chbase = bru * 32 + gu * 8;
  if (hfu == 0) {
    s_den[(bru * 4 + gu) * 64 + w] = den;
#pragma unroll
    for (int c = 0; c < 8; c++) s_val[(chbase + c) * 64 + w] = acc[c];
  }
  __syncthreads();
  if (hfu == 1) {
    const float inv = 1.f / (s_den[(bru * 4 + gu) * 64 + w] + den);
#pragma unroll
    for (int c = 0; c < 8; c++)
      s_val[(chbase + c) * 64 + w] =
          (s_val[(chbase + c) * 64 + w] + acc[c]) * inv;
  }
  __syncthreads();

  // ===== fused final conv1x1 (64->64) + BN: 16 o-groups x 64 w =====
  {
    const int og = __builtin_amdgcn_readfirstlane(tid >> 6);  // 0..15
    float facc[4];
#pragma unroll
    for (int oo = 0; oo < 4; oo++) facc[oo] = 0.f;
    const float* dyt = ws + OFF_DYT + og * 4;
#pragma unroll
    for (int i = 0; i < 64; i++) {
      const float v = s_val[i * 64 + w];
#pragma unroll
      for (int oo = 0; oo < 4; oo++) facc[oo] += dyt[i * 64 + oo] * v;
    }
#pragma unroll
    for (int oo = 0; oo < 4; oo++) {
      const int oc = og * 4 + oo;
      const float sc = dy_g[oc] * rsqrtf(dy_v[oc] + EPSV);
      out[((size_t)(b * 64 + oc)) * 4096 + h * 64 + w] =
          (facc[oo] - dy_m[oc]) * sc + dy_b[oc];
    }
  }
}

// ---------------------------------------------------------------------------
extern "C" void kernel_launch(void* const* d_in, const int* in_sizes, int n_in,
                              void* d_out, int out_size, void* d_ws, size_t ws_size,
                              hipStream_t stream)
{
  const float* x      = (const float*)d_in[0];
  const float* wq_w   = (const float*)d_in[1];
  const float* wq_g   = (const float*)d_in[2];
  const float* wq_b   = (const float*)d_in[3];
  const float* wq_m   = (const float*)d_in[4];
  const float* wq_v   = (const float*)d_in[5];
  const float* wk_w   = (const float*)d_in[6];
  const float* wk_g   = (const float*)d_in[7];
  const float* wk_b   = (const float*)d_in[8];
  const float* wk_m   = (const float*)d_in[9];
  const float* wk_v   = (const float*)d_in[10];
  const float* proj_w = (const float*)d_in[11];
  const float* proj_b = (const float*)d_in[12];
  const float* rpb1   = (const float*)d_in[13];
  const float* rpb2   = (const float*)d_in[14];
  const float* dy_w   = (const float*)d_in[15];
  const float* dy_g   = (const float*)d_in[16];
  const float* dy_b   = (const float*)d_in[17];
  const float* dy_m   = (const float*)d_in[18];
  const float* dy_v   = (const float*)d_in[19];

  float* ws = (float*)d_ws;

  pool_prep_kernel<<<64, 256, 0, stream>>>(x, wk_w, wk_g, wk_b, wk_m, wk_v,
                                           wq_w, wq_g, wq_b, wq_m, wq_v,
                                           dy_w, ws);
  fold_w_kernel<<<32, 256, 0, stream>>>(proj_w, ws, ws + OFF_W);
  contmix_main<<<512, 1024, 0, stream>>>(x, proj_b, rpb1, rpb2,
                                         dy_g, dy_b, dy_m, dy_v,
                                         ws, (float*)d_out);
}

// Round 9
// 167.001 us; speedup vs baseline: 1.0379x; 1.0379x over previous
//
#include <hip/hip_runtime.h>

#define EPSV 1e-5f

// Workspace layout (floats):
//   kbuf @ 0     : [b][g][c][l]  8*4*8*49 = 12544
//   W    @ 12544 : [b][g][o<74][c<8]      = 18944   (W = proj_w @ k^T)
//   wq2  @ 31488 : [o][i] 32*32 (BN+scale folded, row-major like wq_w) = 1024
//   q0   @ 32512 : [o] 32  (folded BN bias * 0.25)  = 32
//   dyT  @ 32544 : [i][o] 64*64                      = 4096
#define OFF_W    12544
#define OFF_WQ2  31488
#define OFF_Q0   32512
#define OFF_DYT  32544

typedef float f4u __attribute__((ext_vector_type(4), aligned(4)));

// ---------------------------------------------------------------------------
// Merged: blocks 0..55 = pool kctx->7x7 + wk conv + BN (kbuf [b][g][c][l]);
// blocks 56..63 = weight prep (wq2/q0 folded BN, dyT transpose).
// ---------------------------------------------------------------------------
__global__ __launch_bounds__(256) void pool_prep_kernel(
    const float* __restrict__ x,
    const float* __restrict__ wk_w, const float* __restrict__ wk_g,
    const float* __restrict__ wk_b, const float* __restrict__ wk_m,
    const float* __restrict__ wk_v,
    const float* __restrict__ wq_w, const float* __restrict__ wq_g,
    const float* __restrict__ wq_b, const float* __restrict__ wq_m,
    const float* __restrict__ wq_v,
    const float* __restrict__ dy_w,
    float* __restrict__ ws)
{
  __shared__ float s_tmp[32 * 64];
  __shared__ float s_kp[32 * 7];
  const int tid = threadIdx.x;

  if (blockIdx.x >= 56) {
    const int t = (blockIdx.x - 56) * 256 + tid;  // 0..2047
    for (int idx = t; idx < 1056; idx += 2048) {
      if (idx < 1024) {
        const int o = idx >> 5;
        const float s = wq_g[o] * rsqrtf(wq_v[o] + EPSV);
        ws[OFF_WQ2 + idx] = 0.25f * s * wq_w[idx];  // same [o][i] layout
      } else {
        const int o = idx - 1024;
        const float s = wq_g[o] * rsqrtf(wq_v[o] + EPSV);
        ws[OFF_Q0 + o] = 0.25f * (wq_b[o] - wq_m[o] * s);
      }
    }
    for (int idx = t; idx < 4096; idx += 2048) {
      const int i = idx >> 6, o = idx & 63;
      ws[OFF_DYT + idx] = dy_w[o * 64 + i];
    }
    return;
  }

  const int b = blockIdx.x / 7;
  const int p = blockIdx.x % 7;
  const int sh = (p * 64) / 7, eh = ((p + 1) * 64 + 6) / 7;
  const float invH = 1.0f / (float)(eh - sh);
  for (int idx = tid; idx < 2048; idx += 256) {
    const int c = idx >> 6, ww = idx & 63;
    const float* xp = x + ((size_t)(b * 64 + 32 + c)) * 4096 + ww;
    float s = 0.f;
    for (int hh = sh; hh < eh; ++hh) s += xp[hh * 64];
    s_tmp[idx] = s * invH;
  }
  __syncthreads();
  if (tid < 224) {
    const int c = tid / 7, q = tid % 7;
    const int sw = (q * 64) / 7, ew = ((q + 1) * 64 + 6) / 7;
    float s = 0.f;
    for (int ww = sw; ww < ew; ++ww) s += s_tmp[c * 64 + ww];
    s_kp[c * 7 + q] = s / (float)(ew - sw);
  }
  __syncthreads();
  if (tid < 224) {
    const int o = tid / 7, q = tid % 7;
    float s = 0.f;
#pragma unroll
    for (int i = 0; i < 32; i++) s += wk_w[o * 32 + i] * s_kp[i * 7 + q];
    const float sc = wk_g[o] * rsqrtf(wk_v[o] + EPSV);
    const int g = o >> 3, c = o & 7, l = p * 7 + q;
    ws[(((size_t)b * 4 + g) * 8 + c) * 49 + l] = (s - wk_m[o]) * sc + wk_b[o];
  }
}

// ---------------------------------------------------------------------------
// W[bg][o][c] = sum_l proj_w[o][l] * k[bg][c][l].
// ---------------------------------------------------------------------------
__global__ __launch_bounds__(256) void fold_w_kernel(
    const float* __restrict__ proj_w, const float* __restrict__ ws_in,
    float* __restrict__ Wout)
{
  const int bg = blockIdx.x;
  const int tid = threadIdx.x;
  __shared__ float s_k[392];
  for (int i = tid; i < 392; i += 256) s_k[i] = ws_in[(size_t)bg * 392 + i];
  __syncthreads();
  for (int idx = tid; idx < 592; idx += 256) {
    const int o = idx >> 3, c = idx & 7;
    float s = 0.f;
#pragma unroll
    for (int l = 0; l < 49; l++) s += proj_w[o * 49 + l] * s_k[c * 49 + l];
    Wout[(size_t)bg * 592 + idx] = s;
  }
}

// ---------------------------------------------------------------------------
// Row-streamed partial attention: rows [R0,R1): logits -> exp -> AV per row,
// so only l[K] (<=7 floats) is live. Partial denom + unscaled AV are additive
// across row subsets -> two threads per (branch,head,pixel) combine exactly.
// ---------------------------------------------------------------------------
template <int K, int R0, int R1, int PBASE>
__device__ __forceinline__ void attn_part(
    const float* __restrict__ Wr, const float* __restrict__ proj_b,
    const float* __restrict__ rp, const float* __restrict__ vb,
    int si, int sj, const float* q8, float* acc, float& den)
{
  constexpr int RS = 2 * K - 1;
  den = 0.f;
#pragma unroll
  for (int c = 0; c < 8; c++) acc[c] = 0.f;
#pragma unroll
  for (int i = R0; i < R1; i++) {
    float l[K];
#pragma unroll
    for (int j = 0; j < K; j++) {
      const int p = PBASE + i * K + j;
      const float* wo = Wr + p * 8;
      float s = proj_b[p];
#pragma unroll
      for (int c = 0; c < 8; c++) s += wo[c] * q8[c];
      l[j] = __expf(s + rp[i * RS + j]);
      den += l[j];
    }
    const float* vr0 = vb + (si + i) * 64 + sj;
#pragma unroll
    for (int c = 0; c < 8; c++) {
      const float* vr = vr0 + c * 4096;
      if constexpr (K == 5) {
        const f4u f = *(const f4u*)vr;
        const float v4 = vr[4];
        acc[c] += l[0] * f.x + l[1] * f.y + l[2] * f.z + l[3] * f.w + l[4] * v4;
      } else {
        const f4u fa = *(const f4u*)vr;
        const f4u fb = *(const f4u*)(vr + 3);
        acc[c] += l[0] * fa.x + l[1] * fa.y + l[2] * fa.z + l[3] * fa.w +
                  l[4] * fb.y + l[5] * fb.z + l[6] * fb.w;
      }
    }
  }
}

// ---------------------------------------------------------------------------
// Fused main. Block = 1024 = 2 halves x 2 branches x 4 heads x 64 w, one row.
// Phase 1 computes q ONCE into LDS (no 4x redundancy); attention threads read
// q8 from LDS. launch_bounds(1024,8) pins VGPR<=64; live set ~35 -> no spill.
// ---------------------------------------------------------------------------
__global__ __launch_bounds__(1024, 8) void contmix_main(
    const float* __restrict__ x,
    const float* __restrict__ proj_b,
    const float* __restrict__ rpb1, const float* __restrict__ rpb2,
    const float* __restrict__ dy_g, const float* __restrict__ dy_b,
    const float* __restrict__ dy_m, const float* __restrict__ dy_v,
    const float* __restrict__ ws,
    float* __restrict__ out)
{
  __shared__ float s_val[64 * 64];  // [ch][w]: half-0 partial, then final
  __shared__ float s_xa[32 * 64];   // [c][w] q-input row
  __shared__ float s_q[32 * 64];    // [qc][w] q values
  __shared__ float s_den[512];      // [br][g][w] half-0 partial denom
  __shared__ float s_rpb1[324];
  __shared__ float s_rpb2[676];

  const int b = blockIdx.x >> 6;
  const int h = blockIdx.x & 63;
  const int tid = threadIdx.x;
  const int w = tid & 63;
  const int gu  = __builtin_amdgcn_readfirstlane((tid >> 6) & 3);
  const int bru = __builtin_amdgcn_readfirstlane((tid >> 8) & 1);
  const int hfu = __builtin_amdgcn_readfirstlane(tid >> 9);

  const float* xb = x + (size_t)b * 64 * 4096;

  // ---- phase 0: stage q-input channels + rpb tables ----
  {
    const float* xr = xb + h * 64;
#pragma unroll
    for (int idx = tid; idx < 2048; idx += 1024)
      s_xa[idx] = xr[(size_t)(idx >> 6) * 4096 + (idx & 63)];
  }
  for (int i = tid; i < 324; i += 1024) s_rpb1[i] = rpb1[i];
  for (int i = tid; i < 676; i += 1024) s_rpb2[i] = rpb2[i];
  __syncthreads();

  // ---- phase 1: q (BN+scale folded) computed once, 2 channels/thread ----
  {
    const int oc0 = __builtin_amdgcn_readfirstlane((tid >> 6) * 2);
    const float* wr0 = ws + OFF_WQ2 + oc0 * 32;
    const float* wr1 = wr0 + 32;
    float a0 = ws[OFF_Q0 + oc0];
    float a1 = ws[OFF_Q0 + oc0 + 1];
#pragma unroll
    for (int i = 0; i < 32; i++) {
      const float xv = s_xa[i * 64 + w];
      a0 += wr0[i] * xv;
      a1 += wr1[i] * xv;
    }
    s_q[oc0 * 64 + w] = a0;
    s_q[(oc0 + 1) * 64 + w] = a1;
  }
  __syncthreads();

  // ---- phase 2: partial attention ----
  float q8[8];
#pragma unroll
  for (int c = 0; c < 8; c++) q8[c] = s_q[(gu * 8 + c) * 64 + w];

  const float* Wr = ws + OFF_W + (size_t)(b * 4 + gu) * 592;  // uniform
  const int ph = 63 - h, pw = 63 - w;

  float acc[8];
  float den;
  if (bru == 0) {
    const int bih = ph - min(max(ph - 2, 0), 59);
    const int biw = pw - min(max(pw - 2, 0), 59);
    const int si = min(max(h - 2, 0), 59), sj = min(max(w - 2, 0), 59);
    const float* rp = s_rpb1 + gu * 81 + bih * 9 + biw;
    const float* vb = xb + gu * 8 * 4096;
    if (hfu == 0)
      attn_part<5, 0, 3, 0>(Wr, proj_b, rp, vb, si, sj, q8, acc, den);
    else
      attn_part<5, 3, 5, 0>(Wr, proj_b, rp, vb, si, sj, q8, acc, den);
  } else {
    const int bih = ph - min(max(ph - 3, 0), 57);
    const int biw = pw - min(max(pw - 3, 0), 57);
    const int si = min(max(h - 3, 0), 57), sj = min(max(w - 3, 0), 57);
    const float* rp = s_rpb2 + gu * 169 + bih * 13 + biw;
    const float* vb = xb + (32 + gu * 8) * 4096;
    if (hfu == 0)
      attn_part<7, 0, 4, 25>(Wr, proj_b, rp, vb, si, sj, q8, acc, den);
    else
      attn_part<7, 4, 7, 25>(Wr, proj_b, rp, vb, si, sj, q8, acc, den);
  }

  const int chbase = bru * 32 + gu * 8;
  if (hfu == 0) {
    s_den[(bru * 4 + gu) * 64 + w] = den;
#pragma unroll
    for (int c = 0; c < 8; c++) s_val[(chbase + c) * 64 + w] = acc[c];
  }
  __syncthreads();
  if (hfu == 1) {
    const float inv = 1.f / (s_den[(bru * 4 + gu) * 64 + w] + den);
#pragma unroll
    for (int c = 0; c < 8; c++)
      s_val[(chbase + c) * 64 + w] =
          (s_val[(chbase + c) * 64 + w] + acc[c]) * inv;
  }
  __syncthreads();

  // ---- phase 3: fused final conv1x1 (64->64) + BN: 16 o-groups x 64 w ----
  {
    const int og = __builtin_amdgcn_readfirstlane(tid >> 6);  // 0..15
    float facc[4];
#pragma unroll
    for (int oo = 0; oo < 4; oo++) facc[oo] = 0.f;
    const float* dyt = ws + OFF_DYT + og * 4;
#pragma unroll
    for (int i = 0; i < 64; i++) {
      const float v = s_val[i * 64 + w];
#pragma unroll
      for (int oo = 0; oo < 4; oo++) facc[oo] += dyt[i * 64 + oo] * v;
    }
#pragma unroll
    for (int oo = 0; oo < 4; oo++) {
      const int oc = og * 4 + oo;
      const float sc = dy_g[oc] * rsqrtf(dy_v[oc] + EPSV);
      out[((size_t)(b * 64 + oc)) * 4096 + h * 64 + w] =
          (facc[oo] - dy_m[oc]) * sc + dy_b[oc];
    }
  }
}

// ---------------------------------------------------------------------------
extern "C" void kernel_launch(void* const* d_in, const int* in_sizes, int n_in,
                              void* d_out, int out_size, void* d_ws, size_t ws_size,
                              hipStream_t stream)
{
  const float* x      = (const float*)d_in[0];
  const float* wq_w   = (const float*)d_in[1];
  const float* wq_g   = (const float*)d_in[2];
  const float* wq_b   = (const float*)d_in[3];
  const float* wq_m   = (const float*)d_in[4];
  const float* wq_v   = (const float*)d_in[5];
  const float* wk_w   = (const float*)d_in[6];
  const float* wk_g   = (const float*)d_in[7];
  const float* wk_b   = (const float*)d_in[8];
  const float* wk_m   = (const float*)d_in[9];
  const float* wk_v   = (const float*)d_in[10];
  const float* proj_w = (const float*)d_in[11];
  const float* proj_b = (const float*)d_in[12];
  const float* rpb1   = (const float*)d_in[13];
  const float* rpb2   = (const float*)d_in[14];
  const float* dy_w   = (const float*)d_in[15];
  const float* dy_g   = (const float*)d_in[16];
  const float* dy_b   = (const float*)d_in[17];
  const float* dy_m   = (const float*)d_in[18];
  const float* dy_v   = (const float*)d_in[19];

  float* ws = (float*)d_ws;

  pool_prep_kernel<<<64, 256, 0, stream>>>(x, wk_w, wk_g, wk_b, wk_m, wk_v,
                                           wq_w, wq_g, wq_b, wq_m, wq_v,
                                           dy_w, ws);
  fold_w_kernel<<<32, 256, 0, stream>>>(proj_w, ws, ws + OFF_W);
  contmix_main<<<512, 1024, 0, stream>>>(x, proj_b, rpb1, rpb2,
                                         dy_g, dy_b, dy_m, dy_v,
                                         ws, (float*)d_out);
}